// Round 7
// baseline (16540.140 us; speedup 1.0000x reference)
//
#include <hip/hip_runtime.h>
#include <hip/hip_bf16.h>
#include <math.h>

// ---------------------------------------------------------------------------
// Stacked LSTM S=512, B=64, I=512, H=1024, L=4 — SEQUENTIAL per-layer
// persistent cooperative kernels. Round-6 (PASSED, 16.5ms): write-through
// relaxed-agent h publish + coherence-point h reads + fence-free barrier
// (no wbl2 / no L2 invalidate per step).
// Round-7 delta (single axis, barrier internals only): the 256-flag barrier
// had ALL 65536 threads spin-polling 8 IF$ cache lines -> request storm that
// queues the useful h stores/loads at the coherence point. Replaced by 8
// monotone arrival COUNTERS (one per 32 WGs, each on its own 128B line):
//   arrive: syncthreads (vmcnt drain = h stores durable at IF$) then tid0
//           does one relaxed agent fetch_add(+1).
//   wait:   threads 0..7 poll one counter each (s_sleep(2) backoff) until
//           counter >= 32*phase, then syncthreads releases the WG.
// Poller count: 65536 -> 2048 (with backoff); ordering argument identical
// to round-6's proven one. Everything else byte-identical to round 6.
// ---------------------------------------------------------------------------

typedef _Float16 f16x8 __attribute__((ext_vector_type(8)));
typedef _Float16 f16x4 __attribute__((ext_vector_type(4)));
typedef float    f32x4 __attribute__((ext_vector_type(4)));

#define S_LEN 512
#define BATCH 64
#define HID   1024
#define GATES 4096
#define NCNT  8
#define CNT_STRIDE 32  // ints -> 128 B per counter line

// ---------------- prep kernels ----------------

__global__ void conv_f32_f16(const float4* __restrict__ in,
                             f16x4* __restrict__ out, int n4) {
  int i = blockIdx.x * blockDim.x + threadIdx.x;
  if (i < n4) {
    float4 v = in[i];
    f16x4 o;
    o[0] = (_Float16)v.x; o[1] = (_Float16)v.y;
    o[2] = (_Float16)v.z; o[3] = (_Float16)v.w;
    out[i] = o;
  }
}

// dst[col][dstOff + k] = (f16) src[k][col], src is [srcK][4096] fp32 row-major.
__global__ void transpose_w(const float* __restrict__ src, int srcK,
                            _Float16* __restrict__ dst, int dstStride, int dstOff) {
  __shared__ float tile[64][65];
  const int kc0 = blockIdx.y * 64;
  const int c0  = blockIdx.x * 64;
  const int tid = threadIdx.x;
  const int r4  = tid >> 6;
  const int cc  = tid & 63;
#pragma unroll
  for (int i = 0; i < 16; ++i) {
    int r = i * 4 + r4;
    tile[r][cc] = src[(size_t)(kc0 + r) * 4096 + c0 + cc];
  }
  __syncthreads();
#pragma unroll
  for (int i = 0; i < 16; ++i) {
    int c = i * 4 + r4;
    dst[(size_t)(c0 + c) * dstStride + dstOff + kc0 + cc] = (_Float16)tile[cc][c];
  }
}

// ---------------- counter-based device barrier ----------------
// Monotone arrival counters, no reset. 8 counters x 32 WGs each; counter k
// reaches 32*phase when all its WGs have published step phase-1.

__device__ __forceinline__ void bar_arrive(int* cnt, int phase) {
  __syncthreads();  // drains each wave's vmcnt -> h write-through stores durable
  if (threadIdx.x == 0)
    __hip_atomic_fetch_add(&cnt[(blockIdx.x >> 5) * CNT_STRIDE], 1,
                           __ATOMIC_RELAXED, __HIP_MEMORY_SCOPE_AGENT);
  (void)phase;
}

__device__ __forceinline__ void bar_wait(int* cnt, int phase) {
  if (threadIdx.x < NCNT) {
    const int target = phase * 32;
    while (__hip_atomic_load(&cnt[threadIdx.x * CNT_STRIDE], __ATOMIC_RELAXED,
                             __HIP_MEMORY_SCOPE_AGENT) < target)
      __builtin_amdgcn_s_sleep(2);
  }
  __syncthreads();
}

// Coherence-point 16B read of h data (2 x 8B relaxed agent atomic loads).
__device__ __forceinline__ f16x8 ld_h8(const _Float16* p) {
  const unsigned long long* q = (const unsigned long long*)p;
  unsigned long long lo = __hip_atomic_load(q, __ATOMIC_RELAXED,
                                            __HIP_MEMORY_SCOPE_AGENT);
  unsigned long long hi = __hip_atomic_load(q + 1, __ATOMIC_RELAXED,
                                            __HIP_MEMORY_SCOPE_AGENT);
  union { unsigned long long u[2]; f16x8 v; } x;
  x.u[0] = lo; x.u[1] = hi;
  return x.v;
}

// ---------------- persistent per-layer LSTM kernel ----------------

template <int KX, bool LAST>
__launch_bounds__(256, 1)
__global__ void lstm_layer(const _Float16* __restrict__ inseq,  // [512][64][KX]
                           _Float16* outseq,                    // [512][64][1024]
                           const _Float16* __restrict__ WT,     // [4096][KX+1024]
                           const float* __restrict__ bias,      // [4096]
                           float* __restrict__ hid32,           // if LAST
                           float* __restrict__ hfin,            // [64][1024]
                           float* __restrict__ cfin,            // [64][1024]
                           int* __restrict__ flags) {           // counters
  constexpr int KTOT = KX + 1024;
  constexpr int XI = KX / 128;
  constexpr int HI = 8;

  const int tid  = threadIdx.x;
  const int lane = tid & 63;
  const int w    = tid >> 6;
  const int n    = lane & 15;
  const int q    = lane >> 4;
  const int cg   = blockIdx.x >> 1;
  const int bg   = blockIdx.x & 1;

  __shared__ float zred[4][32][33];

  // B fragments (wave w holds K-quarter of the WG's 32 packed gate-cols)
  f16x8 bx[XI][2], bh[HI][2];
#pragma unroll
  for (int ct = 0; ct < 2; ++ct) {
    const int p  = ct * 16 + n;
    const int sc = (p >> 3) * 1024 + cg * 8 + (p & 7);
    const _Float16* base = WT + (size_t)sc * KTOT;
#pragma unroll
    for (int i = 0; i < XI; ++i)
      bx[i][ct] = *(const f16x8*)(base + w * (KX / 4) + i * 32 + q * 8);
#pragma unroll
    for (int i = 0; i < HI; ++i)
      bh[i][ct] = *(const f16x8*)(base + KX + w * 256 + i * 32 + q * 8);
  }

  const int erow  = tid >> 3;
  const int ejl   = tid & 7;
  const int grow  = bg * 32 + erow;
  const int ghcol = cg * 8 + ejl;
  const float bi  = bias[ghcol];
  const float bf  = bias[1024 + ghcol];
  const float bgg = bias[2048 + ghcol];
  const float bo  = bias[3072 + ghcol];
  float creg = 0.0f;

  const int arow0 = bg * 32 + n;
  const int arow1 = bg * 32 + 16 + n;

  for (int t = 0; t < S_LEN; ++t) {
    f32x4 acc00 = {}, acc01 = {}, acc10 = {}, acc11 = {};

    // ---- x part (independent of the recurrence -> issued BEFORE the wait)
    {
      const _Float16* xt = inseq + (size_t)t * BATCH * KX;
      const _Float16* a0p = xt + (size_t)arow0 * KX + w * (KX / 4) + q * 8;
      const _Float16* a1p = xt + (size_t)arow1 * KX + w * (KX / 4) + q * 8;
#pragma unroll
      for (int i = 0; i < XI; ++i) {
        f16x8 a0 = *(const f16x8*)(a0p + i * 32);
        f16x8 a1 = *(const f16x8*)(a1p + i * 32);
        acc00 = __builtin_amdgcn_mfma_f32_16x16x32_f16(a0, bx[i][0], acc00, 0, 0, 0);
        acc01 = __builtin_amdgcn_mfma_f32_16x16x32_f16(a0, bx[i][1], acc01, 0, 0, 0);
        acc10 = __builtin_amdgcn_mfma_f32_16x16x32_f16(a1, bx[i][0], acc10, 0, 0, 0);
        acc11 = __builtin_amdgcn_mfma_f32_16x16x32_f16(a1, bx[i][1], acc11, 0, 0, 0);
      }
    }

    // ---- wait for h_{t-1} from all WGs, read at the coherence point
    if (t > 0) {
      bar_wait(flags, t);
      const _Float16* hp = outseq + (size_t)(t - 1) * BATCH * HID;
      const _Float16* a0p = hp + (size_t)arow0 * HID + w * 256 + q * 8;
      const _Float16* a1p = hp + (size_t)arow1 * HID + w * 256 + q * 8;
#pragma unroll
      for (int i = 0; i < HI; ++i) {
        f16x8 a0 = ld_h8(a0p + i * 32);
        f16x8 a1 = ld_h8(a1p + i * 32);
        acc00 = __builtin_amdgcn_mfma_f32_16x16x32_f16(a0, bh[i][0], acc00, 0, 0, 0);
        acc01 = __builtin_amdgcn_mfma_f32_16x16x32_f16(a0, bh[i][1], acc01, 0, 0, 0);
        acc10 = __builtin_amdgcn_mfma_f32_16x16x32_f16(a1, bh[i][0], acc10, 0, 0, 0);
        acc11 = __builtin_amdgcn_mfma_f32_16x16x32_f16(a1, bh[i][1], acc11, 0, 0, 0);
      }
    }

    // ---- K-partial reduce through LDS (C/D: row=q*4+r, col=ct*16+n)
#pragma unroll
    for (int r = 0; r < 4; ++r) {
      zred[w][q * 4 + r][n]           = acc00[r];
      zred[w][q * 4 + r][16 + n]      = acc01[r];
      zred[w][16 + q * 4 + r][n]      = acc10[r];
      zred[w][16 + q * 4 + r][16 + n] = acc11[r];
    }
    __syncthreads();

    float zi = bi, zf = bf, zg = bgg, zo = bo;
#pragma unroll
    for (int ww = 0; ww < 4; ++ww) {
      zi += zred[ww][erow][ejl];
      zf += zred[ww][erow][8 + ejl];
      zg += zred[ww][erow][16 + ejl];
      zo += zred[ww][erow][24 + ejl];
    }
    float ig = 1.0f / (1.0f + __expf(-zi));
    float fg = 1.0f / (1.0f + __expf(-zf));
    float gg = tanhf(zg);
    float og = 1.0f / (1.0f + __expf(-zo));
    float cn = fg * creg + ig * gg;
    float h  = og * tanhf(cn);
    creg = cn;

    const size_t oidx = (size_t)grow * HID + ghcol;

    // ---- h publish: pack 2 adjacent cols (tid, tid^1 same wave) into one
    // 4B write-through relaxed agent atomic store (no dirty-L2 h lines).
    {
      _Float16 hh = (_Float16)h;
      unsigned short hb = __builtin_bit_cast(unsigned short, hh);
      unsigned short pb = (unsigned short)__shfl_xor((int)hb, 1, 64);
      if ((ejl & 1) == 0) {
        unsigned int packed = (unsigned int)hb | ((unsigned int)pb << 16);
        unsigned int* dst =
            (unsigned int*)(outseq + (size_t)t * BATCH * HID + oidx);
        __hip_atomic_store(dst, packed, __ATOMIC_RELAXED,
                           __HIP_MEMORY_SCOPE_AGENT);
      }
    }
    if (LAST) hid32[(size_t)t * BATCH * HID + oidx] = h;
    if (t == S_LEN - 1) { hfin[oidx] = h; cfin[oidx] = cn; }

    if (t + 1 < S_LEN) bar_arrive(flags, t + 1);  // publish h_t
    else __syncthreads();
  }
}

// ---------------- host ----------------

extern "C" void kernel_launch(void* const* d_in, const int* in_sizes, int n_in,
                              void* d_out, int out_size, void* d_ws, size_t ws_size,
                              hipStream_t stream) {
  const float* x_f32   = (const float*)d_in[0];
  const float* Wx0     = (const float*)d_in[1];
  const float* Wh0     = (const float*)d_in[2];
  const float* b0      = (const float*)d_in[3];
  const float* Wx_rest = (const float*)d_in[4];
  const float* Wh_rest = (const float*)d_in[5];
  const float* b_rest  = (const float*)d_in[6];

  float* out = (float*)d_out;
  float* hid_seq = out;                                     // [512,64,1024]
  float* h_fin   = out + (size_t)S_LEN * BATCH * HID;       // [4,64,1024]
  float* c_fin   = h_fin + (size_t)4 * BATCH * HID;         // [4,64,1024]

  size_t off = 0;
  auto alloc = [&](size_t bytes) {
    void* p = (char*)d_ws + off;
    off += (bytes + 255) & ~(size_t)255;
    return p;
  };
  _Float16* WT[4];
  WT[0] = (_Float16*)alloc((size_t)GATES * 1536 * 2);
  WT[1] = (_Float16*)alloc((size_t)GATES * 2048 * 2);
  WT[2] = (_Float16*)alloc((size_t)GATES * 2048 * 2);
  WT[3] = (_Float16*)alloc((size_t)GATES * 2048 * 2);
  _Float16* x16  = (_Float16*)alloc((size_t)S_LEN * BATCH * 512 * 2);
  _Float16* seqA = (_Float16*)alloc((size_t)S_LEN * BATCH * HID * 2);
  _Float16* seqB = (_Float16*)alloc((size_t)S_LEN * BATCH * HID * 2);
  int* flags     = (int*)alloc(4 * NCNT * CNT_STRIDE * sizeof(int));

  // zero barrier counters (ws is poisoned to 0xAA before every call)
  hipMemsetAsync(flags, 0, 4 * NCNT * CNT_STRIDE * sizeof(int), stream);

  // convert x to fp16
  {
    int n4 = S_LEN * BATCH * 512 / 4;
    conv_f32_f16<<<dim3((n4 + 255) / 256), dim3(256), 0, stream>>>(
        (const float4*)x_f32, (f16x4*)x16, n4);
  }

  // fused transposed weights: WT_l[col][k], x rows then h rows
  transpose_w<<<dim3(64, 512 / 64), dim3(256), 0, stream>>>(Wx0, 512, WT[0], 1536, 0);
  transpose_w<<<dim3(64, 1024 / 64), dim3(256), 0, stream>>>(Wh0, 1024, WT[0], 1536, 512);
  for (int l = 1; l < 4; ++l) {
    const float* wx = Wx_rest + (size_t)(l - 1) * 1024 * 4096;
    const float* wh = Wh_rest + (size_t)(l - 1) * 1024 * 4096;
    transpose_w<<<dim3(64, 1024 / 64), dim3(256), 0, stream>>>(wx, 1024, WT[l], 2048, 0);
    transpose_w<<<dim3(64, 1024 / 64), dim3(256), 0, stream>>>(wh, 1024, WT[l], 2048, 1024);
  }

  struct LayerCfg {
    const _Float16* in; _Float16* outp; const _Float16* wt; const float* b;
    float* hid; float* hf; float* cf; int* flg; bool last; int kx;
  } cfg[4] = {
    { x16,  seqA, WT[0], b0,              nullptr, h_fin + 0 * 65536, c_fin + 0 * 65536, flags + 0 * NCNT * CNT_STRIDE, false, 512 },
    { seqA, seqB, WT[1], b_rest + 0*4096, nullptr, h_fin + 1 * 65536, c_fin + 1 * 65536, flags + 1 * NCNT * CNT_STRIDE, false, 1024 },
    { seqB, seqA, WT[2], b_rest + 1*4096, nullptr, h_fin + 2 * 65536, c_fin + 2 * 65536, flags + 2 * NCNT * CNT_STRIDE, false, 1024 },
    { seqA, seqB, WT[3], b_rest + 2*4096, hid_seq, h_fin + 3 * 65536, c_fin + 3 * 65536, flags + 3 * NCNT * CNT_STRIDE, true,  1024 },
  };

  for (int l = 0; l < 4; ++l) {
    const _Float16* pin = cfg[l].in;
    _Float16* pout = cfg[l].outp;
    const _Float16* pwt = cfg[l].wt;
    const float* pb = cfg[l].b;
    float* phid = cfg[l].hid;
    float* phf = cfg[l].hf;
    float* pcf = cfg[l].cf;
    int* pfl = cfg[l].flg;
    void* args[8] = { &pin, &pout, &pwt, &pb, &phid, &phf, &pcf, &pfl };
    if (cfg[l].kx == 512) {
      hipLaunchCooperativeKernel(reinterpret_cast<void*>(&lstm_layer<512, false>),
                                 dim3(256), dim3(256), args, 0, stream);
    } else if (!cfg[l].last) {
      hipLaunchCooperativeKernel(reinterpret_cast<void*>(&lstm_layer<1024, false>),
                                 dim3(256), dim3(256), args, 0, stream);
    } else {
      hipLaunchCooperativeKernel(reinterpret_cast<void*>(&lstm_layer<1024, true>),
                                 dim3(256), dim3(256), args, 0, stream);
    }
  }
}

// Round 8
// 16231.430 us; speedup vs baseline: 1.0190x; 1.0190x over previous
//
#include <hip/hip_runtime.h>
#include <hip/hip_bf16.h>
#include <math.h>

// ---------------------------------------------------------------------------
// Stacked LSTM S=512, B=64, I=512, H=1024, L=4 — SEQUENTIAL per-layer
// persistent cooperative kernels. Round-6 (PASSED 16.5ms): write-through
// relaxed-agent h publish + coherence-point h reads + fence-free barrier.
// Round-7 (NEUTRAL): counter barrier (2k pollers) == flag barrier (65k
// pollers) -> poll contention falsified; step is latency-chain-bound.
// Round-8 delta (single axis): BATCH the h-part's 32 agent-scope atomic
// loads into registers BEFORE the MFMA chain. LLVM preserves atomic-load
// program order and the old source interleaved {2 loads, 4 MFMA} per
// iteration -> ~8-16 SERIALIZED IF$ round-trips (~3-5us/step). Now: all
// loads issue back-to-back (one latency), sched_barrier(0) pins the
// load-phase/MFMA-phase split. +64 VGPR (1 WG/CU, 512-reg budget - free).
// Everything else byte-identical to round 7.
// ---------------------------------------------------------------------------

typedef _Float16 f16x8 __attribute__((ext_vector_type(8)));
typedef _Float16 f16x4 __attribute__((ext_vector_type(4)));
typedef float    f32x4 __attribute__((ext_vector_type(4)));

#define S_LEN 512
#define BATCH 64
#define HID   1024
#define GATES 4096
#define NCNT  8
#define CNT_STRIDE 32  // ints -> 128 B per counter line

// ---------------- prep kernels ----------------

__global__ void conv_f32_f16(const float4* __restrict__ in,
                             f16x4* __restrict__ out, int n4) {
  int i = blockIdx.x * blockDim.x + threadIdx.x;
  if (i < n4) {
    float4 v = in[i];
    f16x4 o;
    o[0] = (_Float16)v.x; o[1] = (_Float16)v.y;
    o[2] = (_Float16)v.z; o[3] = (_Float16)v.w;
    out[i] = o;
  }
}

// dst[col][dstOff + k] = (f16) src[k][col], src is [srcK][4096] fp32 row-major.
__global__ void transpose_w(const float* __restrict__ src, int srcK,
                            _Float16* __restrict__ dst, int dstStride, int dstOff) {
  __shared__ float tile[64][65];
  const int kc0 = blockIdx.y * 64;
  const int c0  = blockIdx.x * 64;
  const int tid = threadIdx.x;
  const int r4  = tid >> 6;
  const int cc  = tid & 63;
#pragma unroll
  for (int i = 0; i < 16; ++i) {
    int r = i * 4 + r4;
    tile[r][cc] = src[(size_t)(kc0 + r) * 4096 + c0 + cc];
  }
  __syncthreads();
#pragma unroll
  for (int i = 0; i < 16; ++i) {
    int c = i * 4 + r4;
    dst[(size_t)(c0 + c) * dstStride + dstOff + kc0 + cc] = (_Float16)tile[cc][c];
  }
}

// ---------------- counter-based device barrier ----------------

__device__ __forceinline__ void bar_arrive(int* cnt, int phase) {
  __syncthreads();  // drains each wave's vmcnt -> h write-through stores durable
  if (threadIdx.x == 0)
    __hip_atomic_fetch_add(&cnt[(blockIdx.x >> 5) * CNT_STRIDE], 1,
                           __ATOMIC_RELAXED, __HIP_MEMORY_SCOPE_AGENT);
  (void)phase;
}

__device__ __forceinline__ void bar_wait(int* cnt, int phase) {
  if (threadIdx.x < NCNT) {
    const int target = phase * 32;
    while (__hip_atomic_load(&cnt[threadIdx.x * CNT_STRIDE], __ATOMIC_RELAXED,
                             __HIP_MEMORY_SCOPE_AGENT) < target)
      __builtin_amdgcn_s_sleep(2);
  }
  __syncthreads();
}

// Coherence-point 16B read of h data (2 x 8B relaxed agent atomic loads).
__device__ __forceinline__ f16x8 ld_h8(const _Float16* p) {
  const unsigned long long* q = (const unsigned long long*)p;
  unsigned long long lo = __hip_atomic_load(q, __ATOMIC_RELAXED,
                                            __HIP_MEMORY_SCOPE_AGENT);
  unsigned long long hi = __hip_atomic_load(q + 1, __ATOMIC_RELAXED,
                                            __HIP_MEMORY_SCOPE_AGENT);
  union { unsigned long long u[2]; f16x8 v; } x;
  x.u[0] = lo; x.u[1] = hi;
  return x.v;
}

// ---------------- persistent per-layer LSTM kernel ----------------

template <int KX, bool LAST>
__launch_bounds__(256, 1)
__global__ void lstm_layer(const _Float16* __restrict__ inseq,  // [512][64][KX]
                           _Float16* outseq,                    // [512][64][1024]
                           const _Float16* __restrict__ WT,     // [4096][KX+1024]
                           const float* __restrict__ bias,      // [4096]
                           float* __restrict__ hid32,           // if LAST
                           float* __restrict__ hfin,            // [64][1024]
                           float* __restrict__ cfin,            // [64][1024]
                           int* __restrict__ flags) {           // counters
  constexpr int KTOT = KX + 1024;
  constexpr int XI = KX / 128;
  constexpr int HI = 8;

  const int tid  = threadIdx.x;
  const int lane = tid & 63;
  const int w    = tid >> 6;
  const int n    = lane & 15;
  const int q    = lane >> 4;
  const int cg   = blockIdx.x >> 1;
  const int bg   = blockIdx.x & 1;

  __shared__ float zred[4][32][33];

  // B fragments (wave w holds K-quarter of the WG's 32 packed gate-cols)
  f16x8 bx[XI][2], bh[HI][2];
#pragma unroll
  for (int ct = 0; ct < 2; ++ct) {
    const int p  = ct * 16 + n;
    const int sc = (p >> 3) * 1024 + cg * 8 + (p & 7);
    const _Float16* base = WT + (size_t)sc * KTOT;
#pragma unroll
    for (int i = 0; i < XI; ++i)
      bx[i][ct] = *(const f16x8*)(base + w * (KX / 4) + i * 32 + q * 8);
#pragma unroll
    for (int i = 0; i < HI; ++i)
      bh[i][ct] = *(const f16x8*)(base + KX + w * 256 + i * 32 + q * 8);
  }

  const int erow  = tid >> 3;
  const int ejl   = tid & 7;
  const int grow  = bg * 32 + erow;
  const int ghcol = cg * 8 + ejl;
  const float bi  = bias[ghcol];
  const float bf  = bias[1024 + ghcol];
  const float bgg = bias[2048 + ghcol];
  const float bo  = bias[3072 + ghcol];
  float creg = 0.0f;

  const int arow0 = bg * 32 + n;
  const int arow1 = bg * 32 + 16 + n;

  for (int t = 0; t < S_LEN; ++t) {
    f32x4 acc00 = {}, acc01 = {}, acc10 = {}, acc11 = {};

    // ---- x part (independent of the recurrence -> issued BEFORE the wait)
    {
      const _Float16* xt = inseq + (size_t)t * BATCH * KX;
      const _Float16* a0p = xt + (size_t)arow0 * KX + w * (KX / 4) + q * 8;
      const _Float16* a1p = xt + (size_t)arow1 * KX + w * (KX / 4) + q * 8;
#pragma unroll
      for (int i = 0; i < XI; ++i) {
        f16x8 a0 = *(const f16x8*)(a0p + i * 32);
        f16x8 a1 = *(const f16x8*)(a1p + i * 32);
        acc00 = __builtin_amdgcn_mfma_f32_16x16x32_f16(a0, bx[i][0], acc00, 0, 0, 0);
        acc01 = __builtin_amdgcn_mfma_f32_16x16x32_f16(a0, bx[i][1], acc01, 0, 0, 0);
        acc10 = __builtin_amdgcn_mfma_f32_16x16x32_f16(a1, bx[i][0], acc10, 0, 0, 0);
        acc11 = __builtin_amdgcn_mfma_f32_16x16x32_f16(a1, bx[i][1], acc11, 0, 0, 0);
      }
    }

    // ---- wait for h_{t-1}, then BATCH all coherent h loads (one IF$
    // latency for the whole phase), then the MFMA chain.
    if (t > 0) {
      bar_wait(flags, t);
      const _Float16* hp = outseq + (size_t)(t - 1) * BATCH * HID;
      const _Float16* a0p = hp + (size_t)arow0 * HID + w * 256 + q * 8;
      const _Float16* a1p = hp + (size_t)arow1 * HID + w * 256 + q * 8;
      f16x8 ha0[HI], ha1[HI];
#pragma unroll
      for (int i = 0; i < HI; ++i) {
        ha0[i] = ld_h8(a0p + i * 32);
        ha1[i] = ld_h8(a1p + i * 32);
      }
      __builtin_amdgcn_sched_barrier(0);  // keep loads clustered before MFMAs
#pragma unroll
      for (int i = 0; i < HI; ++i) {
        acc00 = __builtin_amdgcn_mfma_f32_16x16x32_f16(ha0[i], bh[i][0], acc00, 0, 0, 0);
        acc01 = __builtin_amdgcn_mfma_f32_16x16x32_f16(ha0[i], bh[i][1], acc01, 0, 0, 0);
        acc10 = __builtin_amdgcn_mfma_f32_16x16x32_f16(ha1[i], bh[i][0], acc10, 0, 0, 0);
        acc11 = __builtin_amdgcn_mfma_f32_16x16x32_f16(ha1[i], bh[i][1], acc11, 0, 0, 0);
      }
    }

    // ---- K-partial reduce through LDS (C/D: row=q*4+r, col=ct*16+n)
#pragma unroll
    for (int r = 0; r < 4; ++r) {
      zred[w][q * 4 + r][n]           = acc00[r];
      zred[w][q * 4 + r][16 + n]      = acc01[r];
      zred[w][16 + q * 4 + r][n]      = acc10[r];
      zred[w][16 + q * 4 + r][16 + n] = acc11[r];
    }
    __syncthreads();

    float zi = bi, zf = bf, zg = bgg, zo = bo;
#pragma unroll
    for (int ww = 0; ww < 4; ++ww) {
      zi += zred[ww][erow][ejl];
      zf += zred[ww][erow][8 + ejl];
      zg += zred[ww][erow][16 + ejl];
      zo += zred[ww][erow][24 + ejl];
    }
    float ig = 1.0f / (1.0f + __expf(-zi));
    float fg = 1.0f / (1.0f + __expf(-zf));
    float gg = tanhf(zg);
    float og = 1.0f / (1.0f + __expf(-zo));
    float cn = fg * creg + ig * gg;
    float h  = og * tanhf(cn);
    creg = cn;

    const size_t oidx = (size_t)grow * HID + ghcol;

    // ---- h publish: pack 2 adjacent cols (tid, tid^1 same wave) into one
    // 4B write-through relaxed agent atomic store (no dirty-L2 h lines).
    {
      _Float16 hh = (_Float16)h;
      unsigned short hb = __builtin_bit_cast(unsigned short, hh);
      unsigned short pb = (unsigned short)__shfl_xor((int)hb, 1, 64);
      if ((ejl & 1) == 0) {
        unsigned int packed = (unsigned int)hb | ((unsigned int)pb << 16);
        unsigned int* dst =
            (unsigned int*)(outseq + (size_t)t * BATCH * HID + oidx);
        __hip_atomic_store(dst, packed, __ATOMIC_RELAXED,
                           __HIP_MEMORY_SCOPE_AGENT);
      }
    }
    if (LAST) hid32[(size_t)t * BATCH * HID + oidx] = h;
    if (t == S_LEN - 1) { hfin[oidx] = h; cfin[oidx] = cn; }

    if (t + 1 < S_LEN) bar_arrive(flags, t + 1);  // publish h_t
    else __syncthreads();
  }
}

// ---------------- host ----------------

extern "C" void kernel_launch(void* const* d_in, const int* in_sizes, int n_in,
                              void* d_out, int out_size, void* d_ws, size_t ws_size,
                              hipStream_t stream) {
  const float* x_f32   = (const float*)d_in[0];
  const float* Wx0     = (const float*)d_in[1];
  const float* Wh0     = (const float*)d_in[2];
  const float* b0      = (const float*)d_in[3];
  const float* Wx_rest = (const float*)d_in[4];
  const float* Wh_rest = (const float*)d_in[5];
  const float* b_rest  = (const float*)d_in[6];

  float* out = (float*)d_out;
  float* hid_seq = out;                                     // [512,64,1024]
  float* h_fin   = out + (size_t)S_LEN * BATCH * HID;       // [4,64,1024]
  float* c_fin   = h_fin + (size_t)4 * BATCH * HID;         // [4,64,1024]

  size_t off = 0;
  auto alloc = [&](size_t bytes) {
    void* p = (char*)d_ws + off;
    off += (bytes + 255) & ~(size_t)255;
    return p;
  };
  _Float16* WT[4];
  WT[0] = (_Float16*)alloc((size_t)GATES * 1536 * 2);
  WT[1] = (_Float16*)alloc((size_t)GATES * 2048 * 2);
  WT[2] = (_Float16*)alloc((size_t)GATES * 2048 * 2);
  WT[3] = (_Float16*)alloc((size_t)GATES * 2048 * 2);
  _Float16* x16  = (_Float16*)alloc((size_t)S_LEN * BATCH * 512 * 2);
  _Float16* seqA = (_Float16*)alloc((size_t)S_LEN * BATCH * HID * 2);
  _Float16* seqB = (_Float16*)alloc((size_t)S_LEN * BATCH * HID * 2);
  int* flags     = (int*)alloc(4 * NCNT * CNT_STRIDE * sizeof(int));

  // zero barrier counters (ws is poisoned to 0xAA before every call)
  hipMemsetAsync(flags, 0, 4 * NCNT * CNT_STRIDE * sizeof(int), stream);

  // convert x to fp16
  {
    int n4 = S_LEN * BATCH * 512 / 4;
    conv_f32_f16<<<dim3((n4 + 255) / 256), dim3(256), 0, stream>>>(
        (const float4*)x_f32, (f16x4*)x16, n4);
  }

  // fused transposed weights: WT_l[col][k], x rows then h rows
  transpose_w<<<dim3(64, 512 / 64), dim3(256), 0, stream>>>(Wx0, 512, WT[0], 1536, 0);
  transpose_w<<<dim3(64, 1024 / 64), dim3(256), 0, stream>>>(Wh0, 1024, WT[0], 1536, 512);
  for (int l = 1; l < 4; ++l) {
    const float* wx = Wx_rest + (size_t)(l - 1) * 1024 * 4096;
    const float* wh = Wh_rest + (size_t)(l - 1) * 1024 * 4096;
    transpose_w<<<dim3(64, 1024 / 64), dim3(256), 0, stream>>>(wx, 1024, WT[l], 2048, 0);
    transpose_w<<<dim3(64, 1024 / 64), dim3(256), 0, stream>>>(wh, 1024, WT[l], 2048, 1024);
  }

  struct LayerCfg {
    const _Float16* in; _Float16* outp; const _Float16* wt; const float* b;
    float* hid; float* hf; float* cf; int* flg; bool last; int kx;
  } cfg[4] = {
    { x16,  seqA, WT[0], b0,              nullptr, h_fin + 0 * 65536, c_fin + 0 * 65536, flags + 0 * NCNT * CNT_STRIDE, false, 512 },
    { seqA, seqB, WT[1], b_rest + 0*4096, nullptr, h_fin + 1 * 65536, c_fin + 1 * 65536, flags + 1 * NCNT * CNT_STRIDE, false, 1024 },
    { seqB, seqA, WT[2], b_rest + 1*4096, nullptr, h_fin + 2 * 65536, c_fin + 2 * 65536, flags + 2 * NCNT * CNT_STRIDE, false, 1024 },
    { seqA, seqB, WT[3], b_rest + 2*4096, hid_seq, h_fin + 3 * 65536, c_fin + 3 * 65536, flags + 3 * NCNT * CNT_STRIDE, true,  1024 },
  };

  for (int l = 0; l < 4; ++l) {
    const _Float16* pin = cfg[l].in;
    _Float16* pout = cfg[l].outp;
    const _Float16* pwt = cfg[l].wt;
    const float* pb = cfg[l].b;
    float* phid = cfg[l].hid;
    float* phf = cfg[l].hf;
    float* pcf = cfg[l].cf;
    int* pfl = cfg[l].flg;
    void* args[8] = { &pin, &pout, &pwt, &pb, &phid, &phf, &pcf, &pfl };
    if (cfg[l].kx == 512) {
      hipLaunchCooperativeKernel(reinterpret_cast<void*>(&lstm_layer<512, false>),
                                 dim3(256), dim3(256), args, 0, stream);
    } else if (!cfg[l].last) {
      hipLaunchCooperativeKernel(reinterpret_cast<void*>(&lstm_layer<1024, false>),
                                 dim3(256), dim3(256), args, 0, stream);
    } else {
      hipLaunchCooperativeKernel(reinterpret_cast<void*>(&lstm_layer<1024, true>),
                                 dim3(256), dim3(256), args, 0, stream);
    }
  }
}

// Round 9
// 14232.549 us; speedup vs baseline: 1.1621x; 1.1404x over previous
//
#include <hip/hip_runtime.h>
#include <hip/hip_bf16.h>
#include <math.h>

// ---------------------------------------------------------------------------
// Stacked LSTM S=512, B=64, I=512, H=1024, L=4 — SEQUENTIAL per-layer
// persistent cooperative kernels.
// R6 (PASS 16.5ms): write-through h publish + coherence-point h reads, no
//     per-step L2 flush/invalidate.  R7 (NEUTRAL): poll storm falsified.
// R8 (NEUTRAL): load serialization falsified.
// Round-9 theory: the h-part's agent-scope ATOMIC loads bypass L2 by
// construction -> 256 WGs x 64KB = 16MB/step (128x amplification of the
// 128KB unique h) hits the Infinity Cache every step = ~3.8 TB/s sustained
// coherent-read traffic = the step floor. The x-part (same volume, PLAIN
// loads) is absorbed by L2 because the 32 WGs/XCD share batch rows.
// Round-9 delta (single axis): h-part reads become PLAIN L2-cacheable
// loads. Freshness: h is write-once per launch and every read is
// barrier-ordered after the globally drained write, so L2 lines can only
// be populated with final data; cross-launch reuse hazard removed by
// giving each layer its OWN h buffer (4 x 67MB, ws >= 365MB proven in R4).
// Publish stays write-through relaxed-agent atomic (proven).
// ---------------------------------------------------------------------------

typedef _Float16 f16x8 __attribute__((ext_vector_type(8)));
typedef _Float16 f16x4 __attribute__((ext_vector_type(4)));
typedef float    f32x4 __attribute__((ext_vector_type(4)));

#define S_LEN 512
#define BATCH 64
#define HID   1024
#define GATES 4096
#define NCNT  8
#define CNT_STRIDE 32  // ints -> 128 B per counter line

// ---------------- prep kernels ----------------

__global__ void conv_f32_f16(const float4* __restrict__ in,
                             f16x4* __restrict__ out, int n4) {
  int i = blockIdx.x * blockDim.x + threadIdx.x;
  if (i < n4) {
    float4 v = in[i];
    f16x4 o;
    o[0] = (_Float16)v.x; o[1] = (_Float16)v.y;
    o[2] = (_Float16)v.z; o[3] = (_Float16)v.w;
    out[i] = o;
  }
}

// dst[col][dstOff + k] = (f16) src[k][col], src is [srcK][4096] fp32 row-major.
__global__ void transpose_w(const float* __restrict__ src, int srcK,
                            _Float16* __restrict__ dst, int dstStride, int dstOff) {
  __shared__ float tile[64][65];
  const int kc0 = blockIdx.y * 64;
  const int c0  = blockIdx.x * 64;
  const int tid = threadIdx.x;
  const int r4  = tid >> 6;
  const int cc  = tid & 63;
#pragma unroll
  for (int i = 0; i < 16; ++i) {
    int r = i * 4 + r4;
    tile[r][cc] = src[(size_t)(kc0 + r) * 4096 + c0 + cc];
  }
  __syncthreads();
#pragma unroll
  for (int i = 0; i < 16; ++i) {
    int c = i * 4 + r4;
    dst[(size_t)(c0 + c) * dstStride + dstOff + kc0 + cc] = (_Float16)tile[cc][c];
  }
}

// ---------------- counter-based device barrier ----------------

__device__ __forceinline__ void bar_arrive(int* cnt, int phase) {
  __syncthreads();  // drains each wave's vmcnt -> h write-through stores durable
  if (threadIdx.x == 0)
    __hip_atomic_fetch_add(&cnt[(blockIdx.x >> 5) * CNT_STRIDE], 1,
                           __ATOMIC_RELAXED, __HIP_MEMORY_SCOPE_AGENT);
  (void)phase;
}

__device__ __forceinline__ void bar_wait(int* cnt, int phase) {
  if (threadIdx.x < NCNT) {
    const int target = phase * 32;
    while (__hip_atomic_load(&cnt[threadIdx.x * CNT_STRIDE], __ATOMIC_RELAXED,
                             __HIP_MEMORY_SCOPE_AGENT) < target)
      __builtin_amdgcn_s_sleep(2);
  }
  __syncthreads();
}

// ---------------- persistent per-layer LSTM kernel ----------------

template <int KX, bool LAST>
__launch_bounds__(256, 1)
__global__ void lstm_layer(const _Float16* __restrict__ inseq,  // [512][64][KX]
                           _Float16* outseq,                    // [512][64][1024]
                           const _Float16* __restrict__ WT,     // [4096][KX+1024]
                           const float* __restrict__ bias,      // [4096]
                           float* __restrict__ hid32,           // if LAST
                           float* __restrict__ hfin,            // [64][1024]
                           float* __restrict__ cfin,            // [64][1024]
                           int* __restrict__ flags) {           // counters
  constexpr int KTOT = KX + 1024;
  constexpr int XI = KX / 128;
  constexpr int HI = 8;

  const int tid  = threadIdx.x;
  const int lane = tid & 63;
  const int w    = tid >> 6;
  const int n    = lane & 15;
  const int q    = lane >> 4;
  const int cg   = blockIdx.x >> 1;
  const int bg   = blockIdx.x & 1;

  __shared__ float zred[4][32][33];

  // B fragments (wave w holds K-quarter of the WG's 32 packed gate-cols)
  f16x8 bx[XI][2], bh[HI][2];
#pragma unroll
  for (int ct = 0; ct < 2; ++ct) {
    const int p  = ct * 16 + n;
    const int sc = (p >> 3) * 1024 + cg * 8 + (p & 7);
    const _Float16* base = WT + (size_t)sc * KTOT;
#pragma unroll
    for (int i = 0; i < XI; ++i)
      bx[i][ct] = *(const f16x8*)(base + w * (KX / 4) + i * 32 + q * 8);
#pragma unroll
    for (int i = 0; i < HI; ++i)
      bh[i][ct] = *(const f16x8*)(base + KX + w * 256 + i * 32 + q * 8);
  }

  const int erow  = tid >> 3;
  const int ejl   = tid & 7;
  const int grow  = bg * 32 + erow;
  const int ghcol = cg * 8 + ejl;
  const float bi  = bias[ghcol];
  const float bf  = bias[1024 + ghcol];
  const float bgg = bias[2048 + ghcol];
  const float bo  = bias[3072 + ghcol];
  float creg = 0.0f;

  const int arow0 = bg * 32 + n;
  const int arow1 = bg * 32 + 16 + n;

  for (int t = 0; t < S_LEN; ++t) {
    f32x4 acc00 = {}, acc01 = {}, acc10 = {}, acc11 = {};

    // ---- x part (independent of the recurrence -> issued BEFORE the wait)
    {
      const _Float16* xt = inseq + (size_t)t * BATCH * KX;
      const _Float16* a0p = xt + (size_t)arow0 * KX + w * (KX / 4) + q * 8;
      const _Float16* a1p = xt + (size_t)arow1 * KX + w * (KX / 4) + q * 8;
#pragma unroll
      for (int i = 0; i < XI; ++i) {
        f16x8 a0 = *(const f16x8*)(a0p + i * 32);
        f16x8 a1 = *(const f16x8*)(a1p + i * 32);
        acc00 = __builtin_amdgcn_mfma_f32_16x16x32_f16(a0, bx[i][0], acc00, 0, 0, 0);
        acc01 = __builtin_amdgcn_mfma_f32_16x16x32_f16(a0, bx[i][1], acc01, 0, 0, 0);
        acc10 = __builtin_amdgcn_mfma_f32_16x16x32_f16(a1, bx[i][0], acc10, 0, 0, 0);
        acc11 = __builtin_amdgcn_mfma_f32_16x16x32_f16(a1, bx[i][1], acc11, 0, 0, 0);
      }
    }

    // ---- wait for h_{t-1}, then PLAIN (L2-cacheable) batched h loads.
    // Write-once addresses + barrier ordering => any cached copy is final.
    if (t > 0) {
      bar_wait(flags, t);
      const _Float16* hp = outseq + (size_t)(t - 1) * BATCH * HID;
      const _Float16* a0p = hp + (size_t)arow0 * HID + w * 256 + q * 8;
      const _Float16* a1p = hp + (size_t)arow1 * HID + w * 256 + q * 8;
      f16x8 ha0[HI], ha1[HI];
#pragma unroll
      for (int i = 0; i < HI; ++i) {
        ha0[i] = *(const f16x8*)(a0p + i * 32);
        ha1[i] = *(const f16x8*)(a1p + i * 32);
      }
#pragma unroll
      for (int i = 0; i < HI; ++i) {
        acc00 = __builtin_amdgcn_mfma_f32_16x16x32_f16(ha0[i], bh[i][0], acc00, 0, 0, 0);
        acc01 = __builtin_amdgcn_mfma_f32_16x16x32_f16(ha0[i], bh[i][1], acc01, 0, 0, 0);
        acc10 = __builtin_amdgcn_mfma_f32_16x16x32_f16(ha1[i], bh[i][0], acc10, 0, 0, 0);
        acc11 = __builtin_amdgcn_mfma_f32_16x16x32_f16(ha1[i], bh[i][1], acc11, 0, 0, 0);
      }
    }

    // ---- K-partial reduce through LDS (C/D: row=q*4+r, col=ct*16+n)
#pragma unroll
    for (int r = 0; r < 4; ++r) {
      zred[w][q * 4 + r][n]           = acc00[r];
      zred[w][q * 4 + r][16 + n]      = acc01[r];
      zred[w][16 + q * 4 + r][n]      = acc10[r];
      zred[w][16 + q * 4 + r][16 + n] = acc11[r];
    }
    __syncthreads();

    float zi = bi, zf = bf, zg = bgg, zo = bo;
#pragma unroll
    for (int ww = 0; ww < 4; ++ww) {
      zi += zred[ww][erow][ejl];
      zf += zred[ww][erow][8 + ejl];
      zg += zred[ww][erow][16 + ejl];
      zo += zred[ww][erow][24 + ejl];
    }
    float ig = 1.0f / (1.0f + __expf(-zi));
    float fg = 1.0f / (1.0f + __expf(-zf));
    float gg = tanhf(zg);
    float og = 1.0f / (1.0f + __expf(-zo));
    float cn = fg * creg + ig * gg;
    float h  = og * tanhf(cn);
    creg = cn;

    const size_t oidx = (size_t)grow * HID + ghcol;

    // ---- h publish: pack 2 adjacent cols (tid, tid^1 same wave) into one
    // 4B write-through relaxed agent atomic store (no dirty-L2 h lines).
    {
      _Float16 hh = (_Float16)h;
      unsigned short hb = __builtin_bit_cast(unsigned short, hh);
      unsigned short pb = (unsigned short)__shfl_xor((int)hb, 1, 64);
      if ((ejl & 1) == 0) {
        unsigned int packed = (unsigned int)hb | ((unsigned int)pb << 16);
        unsigned int* dst =
            (unsigned int*)(outseq + (size_t)t * BATCH * HID + oidx);
        __hip_atomic_store(dst, packed, __ATOMIC_RELAXED,
                           __HIP_MEMORY_SCOPE_AGENT);
      }
    }
    if (LAST) hid32[(size_t)t * BATCH * HID + oidx] = h;
    if (t == S_LEN - 1) { hfin[oidx] = h; cfin[oidx] = cn; }

    if (t + 1 < S_LEN) bar_arrive(flags, t + 1);  // publish h_t
    else __syncthreads();
  }
}

// ---------------- host ----------------

extern "C" void kernel_launch(void* const* d_in, const int* in_sizes, int n_in,
                              void* d_out, int out_size, void* d_ws, size_t ws_size,
                              hipStream_t stream) {
  const float* x_f32   = (const float*)d_in[0];
  const float* Wx0     = (const float*)d_in[1];
  const float* Wh0     = (const float*)d_in[2];
  const float* b0      = (const float*)d_in[3];
  const float* Wx_rest = (const float*)d_in[4];
  const float* Wh_rest = (const float*)d_in[5];
  const float* b_rest  = (const float*)d_in[6];

  float* out = (float*)d_out;
  float* hid_seq = out;                                     // [512,64,1024]
  float* h_fin   = out + (size_t)S_LEN * BATCH * HID;       // [4,64,1024]
  float* c_fin   = h_fin + (size_t)4 * BATCH * HID;         // [4,64,1024]

  size_t off = 0;
  auto alloc = [&](size_t bytes) {
    void* p = (char*)d_ws + off;
    off += (bytes + 255) & ~(size_t)255;
    return p;
  };
  _Float16* WT[4];
  WT[0] = (_Float16*)alloc((size_t)GATES * 1536 * 2);
  WT[1] = (_Float16*)alloc((size_t)GATES * 2048 * 2);
  WT[2] = (_Float16*)alloc((size_t)GATES * 2048 * 2);
  WT[3] = (_Float16*)alloc((size_t)GATES * 2048 * 2);
  _Float16* x16  = (_Float16*)alloc((size_t)S_LEN * BATCH * 512 * 2);
  // one DISTINCT h buffer per layer: no cross-launch address reuse
  _Float16* seq[4];
  for (int l = 0; l < 4; ++l)
    seq[l] = (_Float16*)alloc((size_t)S_LEN * BATCH * HID * 2);
  int* flags     = (int*)alloc(4 * NCNT * CNT_STRIDE * sizeof(int));

  // zero barrier counters (ws is poisoned to 0xAA before every call)
  hipMemsetAsync(flags, 0, 4 * NCNT * CNT_STRIDE * sizeof(int), stream);

  // convert x to fp16
  {
    int n4 = S_LEN * BATCH * 512 / 4;
    conv_f32_f16<<<dim3((n4 + 255) / 256), dim3(256), 0, stream>>>(
        (const float4*)x_f32, (f16x4*)x16, n4);
  }

  // fused transposed weights: WT_l[col][k], x rows then h rows
  transpose_w<<<dim3(64, 512 / 64), dim3(256), 0, stream>>>(Wx0, 512, WT[0], 1536, 0);
  transpose_w<<<dim3(64, 1024 / 64), dim3(256), 0, stream>>>(Wh0, 1024, WT[0], 1536, 512);
  for (int l = 1; l < 4; ++l) {
    const float* wx = Wx_rest + (size_t)(l - 1) * 1024 * 4096;
    const float* wh = Wh_rest + (size_t)(l - 1) * 1024 * 4096;
    transpose_w<<<dim3(64, 1024 / 64), dim3(256), 0, stream>>>(wx, 1024, WT[l], 2048, 0);
    transpose_w<<<dim3(64, 1024 / 64), dim3(256), 0, stream>>>(wh, 1024, WT[l], 2048, 1024);
  }

  struct LayerCfg {
    const _Float16* in; _Float16* outp; const _Float16* wt; const float* b;
    float* hid; float* hf; float* cf; int* flg; bool last; int kx;
  } cfg[4] = {
    { x16,    seq[0], WT[0], b0,              nullptr, h_fin + 0 * 65536, c_fin + 0 * 65536, flags + 0 * NCNT * CNT_STRIDE, false, 512 },
    { seq[0], seq[1], WT[1], b_rest + 0*4096, nullptr, h_fin + 1 * 65536, c_fin + 1 * 65536, flags + 1 * NCNT * CNT_STRIDE, false, 1024 },
    { seq[1], seq[2], WT[2], b_rest + 1*4096, nullptr, h_fin + 2 * 65536, c_fin + 2 * 65536, flags + 2 * NCNT * CNT_STRIDE, false, 1024 },
    { seq[2], seq[3], WT[3], b_rest + 2*4096, hid_seq, h_fin + 3 * 65536, c_fin + 3 * 65536, flags + 3 * NCNT * CNT_STRIDE, true,  1024 },
  };

  for (int l = 0; l < 4; ++l) {
    const _Float16* pin = cfg[l].in;
    _Float16* pout = cfg[l].outp;
    const _Float16* pwt = cfg[l].wt;
    const float* pb = cfg[l].b;
    float* phid = cfg[l].hid;
    float* phf = cfg[l].hf;
    float* pcf = cfg[l].cf;
    int* pfl = cfg[l].flg;
    void* args[8] = { &pin, &pout, &pwt, &pb, &phid, &phf, &pcf, &pfl };
    if (cfg[l].kx == 512) {
      hipLaunchCooperativeKernel(reinterpret_cast<void*>(&lstm_layer<512, false>),
                                 dim3(256), dim3(256), args, 0, stream);
    } else if (!cfg[l].last) {
      hipLaunchCooperativeKernel(reinterpret_cast<void*>(&lstm_layer<1024, false>),
                                 dim3(256), dim3(256), args, 0, stream);
    } else {
      hipLaunchCooperativeKernel(reinterpret_cast<void*>(&lstm_layer<1024, true>),
                                 dim3(256), dim3(256), args, 0, stream);
    }
  }
}